// Round 18
// baseline (2321.526 us; speedup 1.0000x reference)
//
#include <hip/hip_runtime.h>
#include <hip/hip_bf16.h>
#include <stdint.h>

#define T_STEPS 512
#define BATCH   64
#define DIN     512
#define DLAT    1024
#define NWG     256          // 64 col-tiles x 4 row-blocks
#define NSLOT   64           // h slot ring (zero = not-yet-written protocol)

typedef __bf16 bf16_t;
typedef __bf16 bf16x4 __attribute__((ext_vector_type(4)));
typedef __bf16 bf16x8 __attribute__((ext_vector_type(8)));
typedef float  f32x4  __attribute__((ext_vector_type(4)));
typedef uint32_t u32x4 __attribute__((ext_vector_type(4)));

// ---- workspace layout (bytes) ----
#define XB_OFF     0u                        // bf16 x [512][64][512] = 33,554,432
#define WXT_OFF    33554432u                 // bf16 x-weights frag-ordered = 4,194,304
#define HWT_OFF    (WXT_OFF + 4194304u)      // bf16 h-weights frag-ordered = 8,388,608
#define HS_OFF     (HWT_OFF + 8388608u)      // bf16 h slots [64][64][1024] = 8,388,608
#define SLOT_ELEMS 65536
#define MEMSET_BYTES 8388608u                // all 64 h slots -> 0 every launch

// ---- LDS: part double-buffered [2][4][64 cols][20 rows] f32 = 40,960 B ----
#define PART_STRIDE_F 5120    // floats per buffer
#define LDS_BYTES  131072     // request clamps occupancy to 1 WG/CU

__global__ void xconv_kernel(const float* __restrict__ x, bf16_t* __restrict__ xb) {
    size_t i = ((size_t)blockIdx.x * 256 + threadIdx.x) * 4;
    const float4 v = *(const float4*)(x + i);
    bf16x4 o;
    o[0] = (bf16_t)v.x; o[1] = (bf16_t)v.y; o[2] = (bf16_t)v.z; o[3] = (bf16_t)v.w;
    *(bf16x4*)(xb + i) = o;
}

// x-weight prep (frag order, verified R10-R17)
__global__ void wxt_prep(const float* __restrict__ Wf, const float* __restrict__ Wi,
                         const float* __restrict__ Wo, const float* __restrict__ Wu,
                         bf16_t* __restrict__ wxt) {
    const int gid  = blockIdx.x * 256 + threadIdx.x;   // 0..262143
    const int lane = gid & 63;
    const int f    = gid >> 6;
    const int cf   = f & 3;
    const int ks   = (f >> 2) & 3;
    const int wv   = (f >> 4) & 3;
    const int ct   = f >> 6;
    const float* Wg = (cf == 0) ? Wf : (cf == 1) ? Wi : (cf == 2) ? Wo : Wu;
    const int k0 = wv * 128 + ks * 32 + (lane >> 4) * 8;
    const int j  = ct * 16 + (lane & 15);
    bf16x8 v;
#pragma unroll
    for (int e = 0; e < 8; ++e) v[e] = (bf16_t)Wg[(size_t)(k0 + e) * DLAT + j];
    *(bf16x8*)(wxt + (size_t)gid * 8) = v;
}

// h-weight prep (frag order, verified R17)
__global__ void hwt_prep(const float* __restrict__ Wf, const float* __restrict__ Wi,
                         const float* __restrict__ Wo, const float* __restrict__ Wu,
                         bf16_t* __restrict__ hwt) {
    const int gid  = blockIdx.x * 256 + threadIdx.x;   // 0..524287
    const int lane = gid & 63;
    const int f    = gid >> 6;
    const int cf   = f & 3;
    const int ks   = (f >> 2) & 7;
    const int wv   = (f >> 5) & 3;
    const int ct   = f >> 7;
    const float* Wg = (cf == 0) ? Wf : (cf == 1) ? Wi : (cf == 2) ? Wo : Wu;
    const int k0 = 512 + wv * 256 + ks * 32 + (lane >> 4) * 8;
    const int j  = ct * 16 + (lane & 15);
    bf16x8 v;
#pragma unroll
    for (int e = 0; e < 8; ++e) v[e] = (bf16_t)Wg[(size_t)(k0 + e) * DLAT + j];
    *(bf16x8*)(hwt + (size_t)gid * 8) = v;
}

__device__ __forceinline__ float rcp_(float x) { return __builtin_amdgcn_rcpf(x); }
__device__ __forceinline__ float sigmoidf_(float v) { return rcp_(1.f + __expf(-v)); }
__device__ __forceinline__ float tanh_fast(float x) {
    const float ax = fabsf(x);
    const float e  = __expf(-2.f * ax);
    const float t  = (1.f - e) * rcp_(1.f + e);
    return copysignf(t, x);
}

// ---- ALL loop vmem is inline-asm with manual vmcnt accounting ----
__device__ __forceinline__ void ld16_sc1(const bf16_t* p, bf16x8& d) {
    f32x4 r;
    asm volatile("global_load_dwordx4 %0, %1, off sc1" : "=v"(r) : "v"(p) : "memory");
    d = __builtin_bit_cast(bf16x8, r);
}
__device__ __forceinline__ void ld16_c(const bf16_t* p, bf16x8& d) {
    f32x4 r;
    asm volatile("global_load_dwordx4 %0, %1, off" : "=v"(r) : "v"(p) : "memory");
    d = __builtin_bit_cast(bf16x8, r);
}
__device__ __forceinline__ void st2_sc1(bf16_t* p, uint32_t bits) {
    asm volatile("global_store_short %0, %1, off sc1" :: "v"(p), "v"(bits) : "memory");
}
__device__ __forceinline__ void st4_c(float* p, float v) {
    asm volatile("global_store_dword %0, %1, off" :: "v"(p), "v"(v) : "memory");
}
#define VMCNT(n) asm volatile("s_waitcnt vmcnt(" #n ")" ::: "memory")

// raw WG barrier: LDS visibility only (vmcnt untouched)
__device__ __forceinline__ void bar_lds() {
    asm volatile("s_waitcnt lgkmcnt(0)" ::: "memory");
    __builtin_amdgcn_s_barrier();
    asm volatile("" ::: "memory");
}

__device__ __forceinline__ bool check_h(const bf16x8 (&ha)[8]) {
    bool ok = true;
#pragma unroll
    for (int ks = 0; ks < 8; ++ks) {
        const u32x4 w = __builtin_bit_cast(u32x4, ha[ks]);
#pragma unroll
        for (int i = 0; i < 4; ++i)
            ok = ok && ((w[i] & 0xFFFFu) != 0u) && ((w[i] & 0xFFFF0000u) != 0u);
    }
    return ok;
}

__launch_bounds__(256, 1)
__global__ void lstm_main(const float* __restrict__ bfp, const float* __restrict__ bip,
                          const float* __restrict__ bop, const float* __restrict__ bup,
                          const bf16_t* __restrict__ xb,
                          const bf16_t* __restrict__ wxt,
                          const bf16_t* __restrict__ hwt,
                          bf16_t* __restrict__ hslots,
                          float* __restrict__ out) {
    extern __shared__ char ldsraw[];
    float* part = (float*)ldsraw;   // [2][4][64 cols][20 rows]

    const int tid  = threadIdx.x;
    const int wv   = tid >> 6;       // wave = k-slice
    const int lane = tid & 63;
    const int lm   = lane & 15;
    const int lq   = lane >> 4;
    const int rb   = blockIdx.x & 3;    // row-block: rows [rb*16, +16)
    const int ct   = blockIdx.x >> 2;   // col-tile: j [ct*16, +16), all 4 gates
    const int r0   = rb * 16;
    const int j0   = ct * 16;

    const int row_l = tid >> 4;          // 0..15
    const int jj    = tid & 15;          // 0..15
    const float bias_r[4] = { bfp[j0 + jj], bip[j0 + jj], bop[j0 + jj], bup[j0 + jj] };
    float cst = 0.f;

    // ---- one-time: ALL weight fragments -> registers (R17-proven) ----
    bf16x8 hwr[32];   // h-weights: [ks 0..7][cf 0..3]
    {
        const bf16_t* hw_base = hwt + (size_t)((ct * 4 + wv) * 32) * 512;
#pragma unroll
        for (int f = 0; f < 32; ++f)
            hwr[f] = *(const bf16x8*)(hw_base + (size_t)f * 512 + lane * 8);
    }
    bf16x8 wxr[16];   // x-weights: [ks 0..3][cf 0..3]
    {
        const bf16_t* wx_base = wxt + (size_t)((ct * 4 + wv) * 16) * 512;
#pragma unroll
        for (int f = 0; f < 16; ++f)
            wxr[f] = *(const bf16x8*)(wx_base + (size_t)f * 512 + lane * 8);
    }

    f32x4 acc0[4], acc1[4];
#pragma unroll
    for (int cf = 0; cf < 4; ++cf) {
        acc0[cf] = (f32x4){0.f, 0.f, 0.f, 0.f};
        acc1[cf] = (f32x4){0.f, 0.f, 0.f, 0.f};
    }

    // reduce+gates+publish for one step (acc -> part[t&1] -> gates -> stores)
    auto finish = [&](int t, f32x4 (&acc)[4]) {
        bf16_t* hnext = hslots + (size_t)((t + 1) & (NSLOT - 1)) * SLOT_ELEMS;
        bf16_t* zslot = hslots + (size_t)((t + 2) & (NSLOT - 1)) * SLOT_ELEMS;
        float* pb = part + (size_t)(t & 1) * PART_STRIDE_F;
#pragma unroll
        for (int cf = 0; cf < 4; ++cf)
            *(f32x4*)&pb[(wv * 64 + cf * 16 + lm) * 20 + lq * 4] = acc[cf];
        bar_lds();   // the ONLY barrier per step (part is double-buffered)
        float gs[4];
#pragma unroll
        for (int g = 0; g < 4; ++g) {
            const int c = g * 16 + jj;
            gs[g] = pb[(0 * 64 + c) * 20 + row_l] + pb[(1 * 64 + c) * 20 + row_l]
                  + pb[(2 * 64 + c) * 20 + row_l] + pb[(3 * 64 + c) * 20 + row_l]
                  + bias_r[g];
        }
        const float ft = sigmoidf_(gs[0]);
        const float it = sigmoidf_(gs[1]);
        const float ot = sigmoidf_(gs[2]);
        const float ut = tanh_fast(gs[3]);
        cst = ft * cst + it * ut;
        const float hv = ot * tanh_fast(cst);
        uint32_t hbits = (uint32_t)__builtin_bit_cast(uint16_t, (bf16_t)hv);
        if (hbits == 0u) hbits = 0x8000u;   // -0.0: 0x0000 never published
        st2_sc1(hnext + (size_t)(r0 + row_l) * DLAT + j0 + jj, hbits);      // store 1
        st2_sc1(zslot + (size_t)(r0 + row_l) * DLAT + j0 + jj, 0u);         // store 2
        st4_c(out + ((size_t)t * BATCH + r0 + row_l) * DLAT + j0 + jj, hv); // store 3
#pragma unroll
        for (int cf = 0; cf < 4; ++cf) acc[cf] = (f32x4){0.f, 0.f, 0.f, 0.f};
    };

    // one main-loop step: acc holds x(t); x(t+1) computed into accN under h RT
    auto body = [&](int t, f32x4 (&acc)[4], f32x4 (&accN)[4]) {
        const bf16_t* hprev = hslots + (size_t)(t & (NSLOT - 1)) * SLOT_ELEMS;
        const int tn = (t + 1 < T_STEPS) ? (t + 1) : (T_STEPS - 1);

        // issue x(t+1) loads (cached) then h(t) loads (sc1): h publishes of
        // step t just committed (lockstep), so first try usually succeeds
        bf16x8 xa[4];
        const bf16_t* xsrc = xb + (size_t)tn * (BATCH * DIN)
                           + (size_t)(r0 + lm) * DIN + wv * 128 + lq * 8;
#pragma unroll
        for (int ks = 0; ks < 4; ++ks) ld16_c(xsrc + ks * 32, xa[ks]);
        bf16x8 ha[8];
        const bf16_t* hb = hprev + (size_t)(r0 + lm) * DLAT + wv * 256 + lq * 8;
#pragma unroll
        for (int ks = 0; ks < 8; ++ks) ld16_sc1(hb + ks * 32, ha[ks]);

        // outstanding: <=3 older stores + 4 xa + 8 ha. vmcnt(8): ha are the
        // 8 newest, so stores+xa retired (in-order retirement).
        VMCNT(8);
        __builtin_amdgcn_sched_barrier(0);
#pragma unroll
        for (int ks = 0; ks < 4; ++ks)
#pragma unroll
            for (int cf = 0; cf < 4; ++cf)
                accN[cf] = __builtin_amdgcn_mfma_f32_16x16x32_bf16(xa[ks], wxr[ks * 4 + cf], accN[cf], 0, 0, 0);

        VMCNT(0);
        __builtin_amdgcn_sched_barrier(0);
        while (!__all(check_h(ha))) {      // self-validating h (R13/R17-proven)
#pragma unroll
            for (int ks = 0; ks < 8; ++ks) ld16_sc1(hb + ks * 32, ha[ks]);
            VMCNT(0);
            __builtin_amdgcn_sched_barrier(0);
        }
#pragma unroll
        for (int ks = 0; ks < 8; ++ks)
#pragma unroll
            for (int cf = 0; cf < 4; ++cf)
                acc[cf] = __builtin_amdgcn_mfma_f32_16x16x32_bf16(ha[ks], hwr[ks * 4 + cf], acc[cf], 0, 0, 0);

        finish(t, acc);
    };

    // ---- prologue: x(0) GEMM (compiler loads; nothing of ours in flight) ----
    {
        const bf16_t* xa = xb + (size_t)(r0 + lm) * DIN + wv * 128 + lq * 8;
#pragma unroll
        for (int ks = 0; ks < 4; ++ks) {
            const bf16x8 a = *(const bf16x8*)(xa + ks * 32);
#pragma unroll
            for (int cf = 0; cf < 4; ++cf)
                acc0[cf] = __builtin_amdgcn_mfma_f32_16x16x32_bf16(a, wxr[ks * 4 + cf], acc0[cf], 0, 0, 0);
        }
    }
    // step 0: h_0 = 0 (no h-GEMM); publish h(1)
    finish(0, acc0);
    VMCNT(0);   // drain step-0 stores before compiler x(1) loads
    {
        const bf16_t* xa = xb + (size_t)(BATCH * DIN)
                         + (size_t)(r0 + lm) * DIN + wv * 128 + lq * 8;
#pragma unroll
        for (int ks = 0; ks < 4; ++ks) {
            const bf16x8 a = *(const bf16x8*)(xa + ks * 32);
#pragma unroll
            for (int cf = 0; cf < 4; ++cf)
                acc0[cf] = __builtin_amdgcn_mfma_f32_16x16x32_bf16(a, wxr[ks * 4 + cf], acc0[cf], 0, 0, 0);
        }
    }

    // ---- main loop: 511 steps, explicit acc ping-pong (no runtime indexing)
    for (int t = 1; t < T_STEPS - 1; t += 2) {
        body(t,     acc0, acc1);
        body(t + 1, acc1, acc0);
    }
    body(T_STEPS - 1, acc0, acc1);   // t = 511 (odd count)
}

extern "C" void kernel_launch(void* const* d_in, const int* in_sizes, int n_in,
                              void* d_out, int out_size, void* d_ws, size_t ws_size,
                              hipStream_t stream) {
    const float* x  = (const float*)d_in[0];
    const float* Wf = (const float*)d_in[1];
    const float* Wi = (const float*)d_in[2];
    const float* Wo = (const float*)d_in[3];
    const float* Wu = (const float*)d_in[4];
    const float* bf = (const float*)d_in[5];
    const float* bi = (const float*)d_in[6];
    const float* bo = (const float*)d_in[7];
    const float* bu = (const float*)d_in[8];
    float* out = (float*)d_out;

    char* ws = (char*)d_ws;
    bf16_t* xb     = (bf16_t*)(ws + XB_OFF);
    bf16_t* wxt    = (bf16_t*)(ws + WXT_OFF);
    bf16_t* hwt    = (bf16_t*)(ws + HWT_OFF);
    bf16_t* hslots = (bf16_t*)(ws + HS_OFF);

    // zero all h slots (0x0000 = unwritten invariant), every replay
    (void)hipMemsetAsync(ws + HS_OFF, 0, MEMSET_BYTES, stream);

    // convert x -> bf16; transpose weights into frag order
    xconv_kernel<<<16384, 256, 0, stream>>>(x, xb);
    wxt_prep<<<1024, 256, 0, stream>>>(Wf, Wi, Wo, Wu, wxt);
    hwt_prep<<<2048, 256, 0, stream>>>(Wf, Wi, Wo, Wu, hwt);

    (void)hipFuncSetAttribute((const void*)lstm_main,
                              hipFuncAttributeMaxDynamicSharedMemorySize, LDS_BYTES);

    lstm_main<<<NWG, 256, LDS_BYTES, stream>>>(bf, bi, bo, bu,
                                               xb, wxt, hwt, hslots, out);
}

// Round 19
// 1642.436 us; speedup vs baseline: 1.4135x; 1.4135x over previous
//
#include <hip/hip_runtime.h>
#include <hip/hip_bf16.h>
#include <stdint.h>

#define T_STEPS 512
#define BATCH   64
#define DIN     512
#define DLAT    1024
#define NWG     256          // 64 col-tiles x 4 row-blocks
#define NSLOT   64           // h slot ring (zero = not-yet-written protocol)

typedef __bf16 bf16_t;
typedef __bf16 bf16x4 __attribute__((ext_vector_type(4)));
typedef __bf16 bf16x8 __attribute__((ext_vector_type(8)));
typedef float  f32x4  __attribute__((ext_vector_type(4)));
typedef uint32_t u32x4 __attribute__((ext_vector_type(4)));

// ---- workspace layout (bytes) ----
#define XB_OFF     0u                        // bf16 x [512][64][512] = 33,554,432
#define WXT_OFF    33554432u                 // bf16 x-weights frag-ordered = 4,194,304
#define HWT_OFF    (WXT_OFF + 4194304u)      // bf16 h-weights frag-ordered = 8,388,608
#define HS_OFF     (HWT_OFF + 8388608u)      // bf16 h slots [64][64][1024] = 8,388,608
#define SLOT_ELEMS 65536
#define MEMSET_BYTES 8388608u                // all 64 h slots -> 0 every launch

// ---- LDS: part double-buffered [2][4][64 cols][20 rows] f32 ----
#define PART_STRIDE_F 5120    // floats per buffer
#define LDS_BYTES  131072     // request clamps occupancy to 1 WG/CU

__global__ void xconv_kernel(const float* __restrict__ x, bf16_t* __restrict__ xb) {
    size_t i = ((size_t)blockIdx.x * 256 + threadIdx.x) * 4;
    const float4 v = *(const float4*)(x + i);
    bf16x4 o;
    o[0] = (bf16_t)v.x; o[1] = (bf16_t)v.y; o[2] = (bf16_t)v.z; o[3] = (bf16_t)v.w;
    *(bf16x4*)(xb + i) = o;
}

// x-weight prep (frag order, verified R10-R17)
__global__ void wxt_prep(const float* __restrict__ Wf, const float* __restrict__ Wi,
                         const float* __restrict__ Wo, const float* __restrict__ Wu,
                         bf16_t* __restrict__ wxt) {
    const int gid  = blockIdx.x * 256 + threadIdx.x;   // 0..262143
    const int lane = gid & 63;
    const int f    = gid >> 6;
    const int cf   = f & 3;
    const int ks   = (f >> 2) & 3;
    const int wv   = (f >> 4) & 3;
    const int ct   = f >> 6;
    const float* Wg = (cf == 0) ? Wf : (cf == 1) ? Wi : (cf == 2) ? Wo : Wu;
    const int k0 = wv * 128 + ks * 32 + (lane >> 4) * 8;
    const int j  = ct * 16 + (lane & 15);
    bf16x8 v;
#pragma unroll
    for (int e = 0; e < 8; ++e) v[e] = (bf16_t)Wg[(size_t)(k0 + e) * DLAT + j];
    *(bf16x8*)(wxt + (size_t)gid * 8) = v;
}

// h-weight prep (frag order, verified R17)
__global__ void hwt_prep(const float* __restrict__ Wf, const float* __restrict__ Wi,
                         const float* __restrict__ Wo, const float* __restrict__ Wu,
                         bf16_t* __restrict__ hwt) {
    const int gid  = blockIdx.x * 256 + threadIdx.x;   // 0..524287
    const int lane = gid & 63;
    const int f    = gid >> 6;
    const int cf   = f & 3;
    const int ks   = (f >> 2) & 7;
    const int wv   = (f >> 5) & 3;
    const int ct   = f >> 7;
    const float* Wg = (cf == 0) ? Wf : (cf == 1) ? Wi : (cf == 2) ? Wo : Wu;
    const int k0 = 512 + wv * 256 + ks * 32 + (lane >> 4) * 8;
    const int j  = ct * 16 + (lane & 15);
    bf16x8 v;
#pragma unroll
    for (int e = 0; e < 8; ++e) v[e] = (bf16_t)Wg[(size_t)(k0 + e) * DLAT + j];
    *(bf16x8*)(hwt + (size_t)gid * 8) = v;
}

__device__ __forceinline__ float rcp_(float x) { return __builtin_amdgcn_rcpf(x); }
__device__ __forceinline__ float sigmoidf_(float v) { return rcp_(1.f + __expf(-v)); }
__device__ __forceinline__ float tanh_fast(float x) {
    const float ax = fabsf(x);
    const float e  = __expf(-2.f * ax);
    const float t  = (1.f - e) * rcp_(1.f + e);
    return copysignf(t, x);
}

// sc1 (MALL-coherent) 16B load, issued without wait
__device__ __forceinline__ bf16x8 ldh16_sc1(const bf16_t* p) {
    f32x4 r;
    asm volatile("global_load_dwordx4 %0, %1, off sc1"
                 : "=v"(r) : "v"(p) : "memory");
    return __builtin_bit_cast(bf16x8, r);
}

// device-scope 2B write-through store
__device__ __forceinline__ void sth2u(bf16_t* p, uint32_t bits) {
    asm volatile("global_store_short %0, %1, off sc1"
                 :: "v"(p), "v"(bits) : "memory");
}

// raw WG barrier: LDS visibility only, does NOT drain vmcnt
__device__ __forceinline__ void bar_lds() {
    asm volatile("s_waitcnt lgkmcnt(0)" ::: "memory");
    __builtin_amdgcn_s_barrier();
    asm volatile("" ::: "memory");
}

__launch_bounds__(256, 1)
__global__ void lstm_main(const float* __restrict__ bfp, const float* __restrict__ bip,
                          const float* __restrict__ bop, const float* __restrict__ bup,
                          const bf16_t* __restrict__ xb,
                          const bf16_t* __restrict__ wxt,
                          const bf16_t* __restrict__ hwt,
                          bf16_t* __restrict__ hslots,
                          float* __restrict__ out) {
    extern __shared__ char ldsraw[];
    float* part = (float*)ldsraw;   // [2][4][64 cols][20 rows]

    const int tid  = threadIdx.x;
    const int wv   = tid >> 6;       // wave = k-slice
    const int lane = tid & 63;
    const int lm   = lane & 15;
    const int lq   = lane >> 4;
    const int rb   = blockIdx.x & 3;    // row-block: rows [rb*16, +16)
    const int ct   = blockIdx.x >> 2;   // col-tile: j [ct*16, +16), all 4 gates
    const int r0   = rb * 16;
    const int j0   = ct * 16;

    const int row_l = tid >> 4;          // 0..15
    const int jj    = tid & 15;          // 0..15
    const float bias_r[4] = { bfp[j0 + jj], bip[j0 + jj], bop[j0 + jj], bup[j0 + jj] };
    float cst = 0.f;

    // ---- one-time: ALL weight fragments -> registers (R17-proven) ----
    bf16x8 hwr[32];   // h-weights: [ks 0..7][cf 0..3]
    {
        const bf16_t* hw_base = hwt + (size_t)((ct * 4 + wv) * 32) * 512;
#pragma unroll
        for (int f = 0; f < 32; ++f)
            hwr[f] = *(const bf16x8*)(hw_base + (size_t)f * 512 + lane * 8);
    }
    bf16x8 wxr[16];   // x-weights: [ks 0..3][cf 0..3]
    {
        const bf16_t* wx_base = wxt + (size_t)((ct * 4 + wv) * 16) * 512;
#pragma unroll
        for (int f = 0; f < 16; ++f)
            wxr[f] = *(const bf16x8*)(wx_base + (size_t)f * 512 + lane * 8);
    }

    f32x4 acc[4];
#pragma unroll
    for (int cf = 0; cf < 4; ++cf) acc[cf] = (f32x4){0.f, 0.f, 0.f, 0.f};

    // reduce+gates+publish for one step: part[t&1], SINGLE barrier per step.
    // WAR safety: reuse of part[(t+1)&1] happens only after bar(t), which
    // all waves reach only after finishing their part[(t-1)&1] reads.
    auto finish = [&](int t, f32x4 (&a)[4]) {
        bf16_t* hnext = hslots + (size_t)((t + 1) & (NSLOT - 1)) * SLOT_ELEMS;
        bf16_t* zslot = hslots + (size_t)((t + 2) & (NSLOT - 1)) * SLOT_ELEMS;
        float* pb = part + (size_t)(t & 1) * PART_STRIDE_F;
#pragma unroll
        for (int cf = 0; cf < 4; ++cf)
            *(f32x4*)&pb[(wv * 64 + cf * 16 + lm) * 20 + lq * 4] = a[cf];
        bar_lds();   // the ONLY barrier per step
        float gs[4];
#pragma unroll
        for (int g = 0; g < 4; ++g) {
            const int c = g * 16 + jj;
            gs[g] = pb[(0 * 64 + c) * 20 + row_l] + pb[(1 * 64 + c) * 20 + row_l]
                  + pb[(2 * 64 + c) * 20 + row_l] + pb[(3 * 64 + c) * 20 + row_l]
                  + bias_r[g];
        }
        const float ft = sigmoidf_(gs[0]);
        const float it = sigmoidf_(gs[1]);
        const float ot = sigmoidf_(gs[2]);
        const float ut = tanh_fast(gs[3]);
        cst = ft * cst + it * ut;
        const float hv = ot * tanh_fast(cst);
        uint32_t hbits = (uint32_t)__builtin_bit_cast(uint16_t, (bf16_t)hv);
        if (hbits == 0u) hbits = 0x8000u;   // -0.0: 0x0000 never published
        sth2u(hnext + (size_t)(r0 + row_l) * DLAT + j0 + jj, hbits);
        sth2u(zslot + (size_t)(r0 + row_l) * DLAT + j0 + jj, 0u);
        out[((size_t)t * BATCH + r0 + row_l) * DLAT + j0 + jj] = hv;  // cached
#pragma unroll
        for (int cf = 0; cf < 4; ++cf) a[cf] = (f32x4){0.f, 0.f, 0.f, 0.f};
    };

    // ---- prologue: x(0) GEMM; step 0 (h_0 = 0, no h-GEMM); x(1) GEMM ----
    {
        const bf16_t* xa = xb + (size_t)(r0 + lm) * DIN + wv * 128 + lq * 8;
#pragma unroll
        for (int ks = 0; ks < 4; ++ks) {
            const bf16x8 a = *(const bf16x8*)(xa + ks * 32);
#pragma unroll
            for (int cf = 0; cf < 4; ++cf)
                acc[cf] = __builtin_amdgcn_mfma_f32_16x16x32_bf16(a, wxr[ks * 4 + cf], acc[cf], 0, 0, 0);
        }
    }
    finish(0, acc);
    asm volatile("s_waitcnt vmcnt(0)" ::: "memory");   // drain step-0 asm stores
    {
        const bf16_t* xa = xb + (size_t)(BATCH * DIN)
                         + (size_t)(r0 + lm) * DIN + wv * 128 + lq * 8;
#pragma unroll
        for (int ks = 0; ks < 4; ++ks) {
            const bf16x8 a = *(const bf16x8*)(xa + ks * 32);
#pragma unroll
            for (int cf = 0; cf < 4; ++cf)
                acc[cf] = __builtin_amdgcn_mfma_f32_16x16x32_bf16(a, wxr[ks * 4 + cf], acc[cf], 0, 0, 0);
        }
    }

    // ---- main loop: acc holds x(t) on entry ----
    for (int t = 1; t < T_STEPS; ++t) {
        const bf16_t* hprev = hslots + (size_t)(t & (NSLOT - 1)) * SLOT_ELEMS;
        const int tn = (t + 1 < T_STEPS) ? (t + 1) : (T_STEPS - 1);

        // h loads (sc1, asm) at the R17-calibrated issue point
        const bf16_t* hb = hprev + (size_t)(r0 + lm) * DLAT + wv * 256 + lq * 8;
        bf16x8 ha[8];
        while (true) {
#pragma unroll
            for (int ks = 0; ks < 8; ++ks) ha[ks] = ldh16_sc1(hb + ks * 32);
            asm volatile("s_waitcnt vmcnt(0)" ::: "memory");
            __builtin_amdgcn_sched_barrier(0);
            bool ok = true;
#pragma unroll
            for (int ks = 0; ks < 8; ++ks) {
                const u32x4 w = __builtin_bit_cast(u32x4, ha[ks]);
#pragma unroll
                for (int i = 0; i < 4; ++i)
                    ok = ok && ((w[i] & 0xFFFFu) != 0u) && ((w[i] & 0xFFFF0000u) != 0u);
            }
            if (__all(ok)) break;
        }

        // hoisted x(t+1) loads (compiler-managed): RT hides under h-MFMA +
        // reduce + barrier + gates; consumed only after finish()
        bf16x8 xv[4];
        {
            const bf16_t* xsrc = xb + (size_t)tn * (BATCH * DIN)
                               + (size_t)(r0 + lm) * DIN + wv * 128 + lq * 8;
#pragma unroll
            for (int ks = 0; ks < 4; ++ks) xv[ks] = *(const bf16x8*)(xsrc + ks * 32);
        }

        // h-MFMA (weights in registers)
#pragma unroll
        for (int ks = 0; ks < 8; ++ks)
#pragma unroll
            for (int cf = 0; cf < 4; ++cf)
                acc[cf] = __builtin_amdgcn_mfma_f32_16x16x32_bf16(ha[ks], hwr[ks * 4 + cf], acc[cf], 0, 0, 0);

        finish(t, acc);

        // x(t+1) GEMM into fresh acc (loads issued ~0.4 us ago -> retired)
#pragma unroll
        for (int ks = 0; ks < 4; ++ks)
#pragma unroll
            for (int cf = 0; cf < 4; ++cf)
                acc[cf] = __builtin_amdgcn_mfma_f32_16x16x32_bf16(xv[ks], wxr[ks * 4 + cf], acc[cf], 0, 0, 0);
    }
}

extern "C" void kernel_launch(void* const* d_in, const int* in_sizes, int n_in,
                              void* d_out, int out_size, void* d_ws, size_t ws_size,
                              hipStream_t stream) {
    const float* x  = (const float*)d_in[0];
    const float* Wf = (const float*)d_in[1];
    const float* Wi = (const float*)d_in[2];
    const float* Wo = (const float*)d_in[3];
    const float* Wu = (const float*)d_in[4];
    const float* bf = (const float*)d_in[5];
    const float* bi = (const float*)d_in[6];
    const float* bo = (const float*)d_in[7];
    const float* bu = (const float*)d_in[8];
    float* out = (float*)d_out;

    char* ws = (char*)d_ws;
    bf16_t* xb     = (bf16_t*)(ws + XB_OFF);
    bf16_t* wxt    = (bf16_t*)(ws + WXT_OFF);
    bf16_t* hwt    = (bf16_t*)(ws + HWT_OFF);
    bf16_t* hslots = (bf16_t*)(ws + HS_OFF);

    // zero all h slots (0x0000 = unwritten invariant), every replay
    (void)hipMemsetAsync(ws + HS_OFF, 0, MEMSET_BYTES, stream);

    // convert x -> bf16; transpose weights into frag order
    xconv_kernel<<<16384, 256, 0, stream>>>(x, xb);
    wxt_prep<<<1024, 256, 0, stream>>>(Wf, Wi, Wo, Wu, wxt);
    hwt_prep<<<2048, 256, 0, stream>>>(Wf, Wi, Wo, Wu, hwt);

    (void)hipFuncSetAttribute((const void*)lstm_main,
                              hipFuncAttributeMaxDynamicSharedMemorySize, LDS_BYTES);

    lstm_main<<<NWG, 256, LDS_BYTES, stream>>>(bf, bi, bo, bu,
                                               xb, wxt, hwt, hslots, out);
}

// Round 21
// 1552.079 us; speedup vs baseline: 1.4958x; 1.0582x over previous
//
#include <hip/hip_runtime.h>
#include <hip/hip_bf16.h>
#include <stdint.h>

#define T_STEPS 512
#define BATCH   64
#define DIN     512
#define DLAT    1024
#define NWG     256          // 64 col-tiles x 4 row-blocks
#define NSLOT   64           // h slot ring (zero = not-yet-written protocol)

typedef __bf16 bf16_t;
typedef __bf16 bf16x4 __attribute__((ext_vector_type(4)));
typedef __bf16 bf16x8 __attribute__((ext_vector_type(8)));
typedef float  f32x4  __attribute__((ext_vector_type(4)));
typedef uint32_t u32x4 __attribute__((ext_vector_type(4)));

// ---- workspace layout (bytes) ----
#define XB_OFF     0u                        // bf16 x [512][64][512] = 33,554,432
#define WXT_OFF    33554432u                 // bf16 x-weights frag-ordered = 4,194,304
#define HWT_OFF    (WXT_OFF + 4194304u)      // bf16 h-weights frag-ordered = 8,388,608
#define HS_OFF     (HWT_OFF + 8388608u)      // bf16 h slots [64][64][1024] = 8,388,608
#define SLOT_ELEMS 65536
#define MEMSET_BYTES 8388608u                // all 64 h slots -> 0 every launch

// ---- LDS (only part-exchange used; large request forces 1 WG/CU) ----
#define PART_OFF_B 0          // f32 [4 waves][64 cols][20 rows-pad] = 20,480
#define LDS_BYTES  131072     // forces 1 WG/CU (occupancy clamp)

__global__ void xconv_kernel(const float* __restrict__ x, bf16_t* __restrict__ xb) {
    size_t i = ((size_t)blockIdx.x * 256 + threadIdx.x) * 4;
    const float4 v = *(const float4*)(x + i);
    bf16x4 o;
    o[0] = (bf16_t)v.x; o[1] = (bf16_t)v.y; o[2] = (bf16_t)v.z; o[3] = (bf16_t)v.w;
    *(bf16x4*)(xb + i) = o;
}

// x-weight prep (frag order, verified R10-R16): frag f = gid>>6;
// cf = f&3 (gate), ks = (f>>2)&3, wv = (f>>4)&3, ct = f>>6.
__global__ void wxt_prep(const float* __restrict__ Wf, const float* __restrict__ Wi,
                         const float* __restrict__ Wo, const float* __restrict__ Wu,
                         bf16_t* __restrict__ wxt) {
    const int gid  = blockIdx.x * 256 + threadIdx.x;   // 0..262143
    const int lane = gid & 63;
    const int f    = gid >> 6;
    const int cf   = f & 3;
    const int ks   = (f >> 2) & 3;
    const int wv   = (f >> 4) & 3;
    const int ct   = f >> 6;
    const float* Wg = (cf == 0) ? Wf : (cf == 1) ? Wi : (cf == 2) ? Wo : Wu;
    const int k0 = wv * 128 + ks * 32 + (lane >> 4) * 8;
    const int j  = ct * 16 + (lane & 15);
    bf16x8 v;
#pragma unroll
    for (int e = 0; e < 8; ++e) v[e] = (bf16_t)Wg[(size_t)(k0 + e) * DLAT + j];
    *(bf16x8*)(wxt + (size_t)gid * 8) = v;
}

// h-weight prep (frag order): frag f = gid>>6 (0..8191);
// cf = f&3 (gate), ks = (f>>2)&7, wv = (f>>5)&3, ct = f>>7.
// elem e: W_gate[512 + wv*256 + ks*32 + (lane>>4)*8 + e][ct*16 + (lane&15)]
__global__ void hwt_prep(const float* __restrict__ Wf, const float* __restrict__ Wi,
                         const float* __restrict__ Wo, const float* __restrict__ Wu,
                         bf16_t* __restrict__ hwt) {
    const int gid  = blockIdx.x * 256 + threadIdx.x;   // 0..524287
    const int lane = gid & 63;
    const int f    = gid >> 6;
    const int cf   = f & 3;
    const int ks   = (f >> 2) & 7;
    const int wv   = (f >> 5) & 3;
    const int ct   = f >> 7;
    const float* Wg = (cf == 0) ? Wf : (cf == 1) ? Wi : (cf == 2) ? Wo : Wu;
    const int k0 = 512 + wv * 256 + ks * 32 + (lane >> 4) * 8;
    const int j  = ct * 16 + (lane & 15);
    bf16x8 v;
#pragma unroll
    for (int e = 0; e < 8; ++e) v[e] = (bf16_t)Wg[(size_t)(k0 + e) * DLAT + j];
    *(bf16x8*)(hwt + (size_t)gid * 8) = v;
}

__device__ __forceinline__ float rcp_(float x) { return __builtin_amdgcn_rcpf(x); }
__device__ __forceinline__ float sigmoidf_(float v) { return rcp_(1.f + __expf(-v)); }
__device__ __forceinline__ float tanh_fast(float x) {
    const float ax = fabsf(x);
    const float e  = __expf(-2.f * ax);
    const float t  = (1.f - e) * rcp_(1.f + e);
    return copysignf(t, x);
}

// sc1 (MALL-coherent) 16B load, issued without wait
__device__ __forceinline__ bf16x8 ldh16_sc1(const bf16_t* p) {
    f32x4 r;
    asm volatile("global_load_dwordx4 %0, %1, off sc1"
                 : "=v"(r) : "v"(p) : "memory");
    return __builtin_bit_cast(bf16x8, r);
}

// device-scope 2B write-through store
__device__ __forceinline__ void sth2u(bf16_t* p, uint32_t bits) {
    asm volatile("global_store_short %0, %1, off sc1"
                 :: "v"(p), "v"(bits) : "memory");
}

// raw WG barrier: LDS visibility only, does NOT drain vmcnt
__device__ __forceinline__ void bar_lds() {
    asm volatile("s_waitcnt lgkmcnt(0)" ::: "memory");
    __builtin_amdgcn_s_barrier();
    asm volatile("" ::: "memory");
}

__launch_bounds__(256, 1)
__global__ void lstm_main(const float* __restrict__ bfp, const float* __restrict__ bip,
                          const float* __restrict__ bop, const float* __restrict__ bup,
                          const bf16_t* __restrict__ xb,
                          const bf16_t* __restrict__ wxt,
                          const bf16_t* __restrict__ hwt,
                          bf16_t* __restrict__ hslots,
                          float* __restrict__ out) {
    extern __shared__ char ldsraw[];
    float* part = (float*)(ldsraw + PART_OFF_B);   // [4][64 cols][20 rows]

    const int tid  = threadIdx.x;
    const int wv   = tid >> 6;       // wave = k-slice
    const int lane = tid & 63;
    const int lm   = lane & 15;
    const int lq   = lane >> 4;
    const int rb   = blockIdx.x & 3;    // row-block: rows [rb*16, +16)
    const int ct   = blockIdx.x >> 2;   // col-tile: j [ct*16, +16), all 4 gates
    const int r0   = rb * 16;
    const int j0   = ct * 16;

    // elementwise ownership: tid = row_l*16 + jj
    const int row_l = tid >> 4;          // 0..15
    const int jj    = tid & 15;          // 0..15
    const float bias_r[4] = { bfp[j0 + jj], bip[j0 + jj], bop[j0 + jj], bup[j0 + jj] };
    float cst = 0.f;

    // ---- one-time: ALL weight fragments -> VGPRs (frag-ordered buffers,
    // contiguous 16B loads; 128 + 64 VGPRs of the 512 budget at 1 wave/SIMD).
    // Removes 32 ds_read_b128 + lgkm waits from every step's critical path.
    bf16x8 hwr[32];   // h-weights: [ks 0..7][cf 0..3]
    {
        const bf16_t* hw_base = hwt + (size_t)((ct * 4 + wv) * 32) * 512;
#pragma unroll
        for (int f = 0; f < 32; ++f)
            hwr[f] = *(const bf16x8*)(hw_base + (size_t)f * 512 + lane * 8);
    }
    bf16x8 wxr[16];   // x-weights: [ks 0..3][cf 0..3]
    {
        const bf16_t* wx_base = wxt + (size_t)((ct * 4 + wv) * 16) * 512;
#pragma unroll
        for (int f = 0; f < 16; ++f)
            wxr[f] = *(const bf16x8*)(wx_base + (size_t)f * 512 + lane * 8);
    }

    f32x4 acc[4];
#pragma unroll
    for (int cf = 0; cf < 4; ++cf) acc[cf] = (f32x4){0.f, 0.f, 0.f, 0.f};

    // ---- prologue: x_0 GEMM (wave x-k slice [wv*128, +128)) ----
    {
        const bf16_t* xa = xb + (size_t)(r0 + lm) * DIN + wv * 128 + lq * 8;
#pragma unroll
        for (int ks = 0; ks < 4; ++ks) {
            const bf16x8 a = *(const bf16x8*)(xa + ks * 32);
#pragma unroll
            for (int cf = 0; cf < 4; ++cf)
                acc[cf] = __builtin_amdgcn_mfma_f32_16x16x32_bf16(a, wxr[ks * 4 + cf], acc[cf], 0, 0, 0);
        }
    }

    for (int t = 0; t < T_STEPS; ++t) {
        const bf16_t* hprev = hslots + (size_t)(t & (NSLOT - 1)) * SLOT_ELEMS;
        bf16_t*       hnext = hslots + (size_t)((t + 1) & (NSLOT - 1)) * SLOT_ELEMS;
        bf16_t*       zslot = hslots + (size_t)((t + 2) & (NSLOT - 1)) * SLOT_ELEMS;

        // ---- h GEMM with self-validating loads (R13-proven): 0x0000 means
        // "not yet written" (producers store -0.0 for true zeros). The
        // successful data load IS the synchronization. (t=0: h_0 = 0, skip.)
        if (t > 0) {
            const bf16_t* hb = hprev + (size_t)(r0 + lm) * DLAT + wv * 256 + lq * 8;
            bf16x8 ha[8];
            while (true) {
#pragma unroll
                for (int ks = 0; ks < 8; ++ks) ha[ks] = ldh16_sc1(hb + ks * 32);
                asm volatile("s_waitcnt vmcnt(0)" ::: "memory");
                __builtin_amdgcn_sched_barrier(0);
                bool ok = true;
#pragma unroll
                for (int ks = 0; ks < 8; ++ks) {
                    const u32x4 w = __builtin_bit_cast(u32x4, ha[ks]);
#pragma unroll
                    for (int i = 0; i < 4; ++i)
                        ok = ok && ((w[i] & 0xFFFFu) != 0u) && ((w[i] & 0xFFFF0000u) != 0u);
                }
                if (__all(ok)) break;
            }
            // pure-register MFMAs (weights already in VGPRs)
#pragma unroll
            for (int ks = 0; ks < 8; ++ks)
#pragma unroll
                for (int cf = 0; cf < 4; ++cf)
                    acc[cf] = __builtin_amdgcn_mfma_f32_16x16x32_bf16(ha[ks], hwr[ks * 4 + cf], acc[cf], 0, 0, 0);
        }

        // ---- cross-wave K-reduction via LDS ----
        // acc[cf][i] = (row = lq*4+i, col = cf*16+lm)
#pragma unroll
        for (int cf = 0; cf < 4; ++cf)
            *(f32x4*)&part[(wv * 64 + cf * 16 + lm) * 20 + lq * 4] = acc[cf];
        bar_lds();   // barrier #1: partials visible (no vmcnt drain)

        float gs[4];
#pragma unroll
        for (int g = 0; g < 4; ++g) {
            const int c = g * 16 + jj;
            gs[g] = part[(0 * 64 + c) * 20 + row_l] + part[(1 * 64 + c) * 20 + row_l]
                  + part[(2 * 64 + c) * 20 + row_l] + part[(3 * 64 + c) * 20 + row_l]
                  + bias_r[g];
        }
        const float ft = sigmoidf_(gs[0]);
        const float it = sigmoidf_(gs[1]);
        const float ot = sigmoidf_(gs[2]);
        const float ut = tanh_fast(gs[3]);
        cst = ft * cst + it * ut;
        const float hv = ot * tanh_fast(cst);

        // ---- publish h_{t+1}: per-thread 2B sc1 store, +0.0 -> -0.0 so the
        // bit pattern 0x0000 never occurs in published data (bit-exact) ----
        {
            uint32_t hbits = (uint32_t)__builtin_bit_cast(uint16_t, (bf16_t)hv);
            if (hbits == 0u) hbits = 0x8000u;   // -0.0, numerically identical
            sth2u(hnext + (size_t)(r0 + row_l) * DLAT + j0 + jj, hbits);
        }
        // zero-ahead: clear our stripe of the slot that will carry h_{t+2}
        // (previous content consumed ~62 steps ago; same-rb chains provably
        // within 1 step of each other — R13 argument)
        sth2u(zslot + (size_t)(r0 + row_l) * DLAT + j0 + jj, 0u);

        bar_lds();   // barrier #2 (WAR on part); stores keep flying

        // out store (cached path)
        out[((size_t)t * BATCH + r0 + row_l) * DLAT + j0 + jj] = hv;

        // ---- overlap: x_{t+1} GEMM into fresh acc ----
#pragma unroll
        for (int cf = 0; cf < 4; ++cf) acc[cf] = (f32x4){0.f, 0.f, 0.f, 0.f};
        if (t + 1 < T_STEPS) {
            const bf16_t* xa = xb + (size_t)(t + 1) * (BATCH * DIN)
                             + (size_t)(r0 + lm) * DIN + wv * 128 + lq * 8;
#pragma unroll
            for (int ks = 0; ks < 4; ++ks) {
                const bf16x8 a = *(const bf16x8*)(xa + ks * 32);
#pragma unroll
                for (int cf = 0; cf < 4; ++cf)
                    acc[cf] = __builtin_amdgcn_mfma_f32_16x16x32_bf16(a, wxr[ks * 4 + cf], acc[cf], 0, 0, 0);
            }
        }
    }
}

extern "C" void kernel_launch(void* const* d_in, const int* in_sizes, int n_in,
                              void* d_out, int out_size, void* d_ws, size_t ws_size,
                              hipStream_t stream) {
    const float* x  = (const float*)d_in[0];
    const float* Wf = (const float*)d_in[1];
    const float* Wi = (const float*)d_in[2];
    const float* Wo = (const float*)d_in[3];
    const float* Wu = (const float*)d_in[4];
    const float* bf = (const float*)d_in[5];
    const float* bi = (const float*)d_in[6];
    const float* bo = (const float*)d_in[7];
    const float* bu = (const float*)d_in[8];
    float* out = (float*)d_out;

    char* ws = (char*)d_ws;
    bf16_t* xb     = (bf16_t*)(ws + XB_OFF);
    bf16_t* wxt    = (bf16_t*)(ws + WXT_OFF);
    bf16_t* hwt    = (bf16_t*)(ws + HWT_OFF);
    bf16_t* hslots = (bf16_t*)(ws + HS_OFF);

    // zero all h slots (0x0000 = unwritten invariant), every replay
    (void)hipMemsetAsync(ws + HS_OFF, 0, MEMSET_BYTES, stream);

    // convert x -> bf16; transpose weights into frag order
    xconv_kernel<<<16384, 256, 0, stream>>>(x, xb);
    wxt_prep<<<1024, 256, 0, stream>>>(Wf, Wi, Wo, Wu, wxt);
    hwt_prep<<<2048, 256, 0, stream>>>(Wf, Wi, Wo, Wu, hwt);

    (void)hipFuncSetAttribute((const void*)lstm_main,
                              hipFuncAttributeMaxDynamicSharedMemorySize, LDS_BYTES);

    lstm_main<<<NWG, 256, LDS_BYTES, stream>>>(bf, bi, bo, bu,
                                               xb, wxt, hwt, hslots, out);
}